// Round 10
// baseline (79.833 us; speedup 1.0000x reference)
//
#include <hip/hip_runtime.h>
#include <hip/hip_bf16.h>

typedef unsigned short u16;
typedef unsigned int u32;
typedef float f32x4 __attribute__((ext_vector_type(4)));
typedef short s16x8 __attribute__((ext_vector_type(8)));

#define MFMA16(a,b,c) __builtin_amdgcn_mfma_f32_16x16x32_bf16((a),(b),(c),0,0,0)

static __device__ __forceinline__ u16 f2bf(float x){
  union { __hip_bfloat16 b; u16 u; } c;
  c.b = __float2bfloat16(x);
  return c.u;
}
static __device__ __forceinline__ u32 pk2(float a, float b){
  return (u32)f2bf(a) | ((u32)f2bf(b) << 16);
}

// lgkm-only barrier (keeps global loads in flight across barriers)
static __device__ __forceinline__ void softbar() {
  __builtin_amdgcn_sched_barrier(0);
  asm volatile("s_waitcnt lgkmcnt(0)" ::: "memory");
  __builtin_amdgcn_s_barrier();
  __builtin_amdgcn_sched_barrier(0);
}

// ---------------------------------------------------------------------------
// prep: build bf16 transposed/permuted weight buffers + gin[:, 0:512]
// ---------------------------------------------------------------------------
__global__ void prep_kernel(const float* __restrict__ Wm1, const float* __restrict__ Wm2,
                            const float* __restrict__ Wm3, const float* __restrict__ Wg1,
                            const float* __restrict__ Wr,  const float* __restrict__ Wt1,
                            const float* __restrict__ node,const float* __restrict__ prev,
                            const float* __restrict__ edge,const float* __restrict__ graph,
                            u16* __restrict__ WbT, u16* __restrict__ WgrT,
                            u16* __restrict__ Wm2T, u16* __restrict__ Wm3T,
                            u16* __restrict__ gin)
{
  int idx = blockIdx.x * 256 + threadIdx.x;
  if (idx < 147456) {                       // WbT: 288*512
    int n = idx >> 9, k = idx & 511;
    int part = k >> 7, kk = k & 127;
    float v = 0.f;
    if (n < 128) {                          // u = z@W_zi + gb@W_g
      if (part == 0)      v = Wm1[kk*128 + n];
      else if (part == 1) v = Wm1[(128+kk)*128 + n];
      else if (part == 3) v = Wm1[(640+kk)*128 + n];
    } else if (n < 256) {                   // v = z@W_zj + edge@W_e
      int nn = n - 128;
      if (part == 0)      v = Wm1[(256+kk)*128 + nn];
      else if (part == 1) v = Wm1[(384+kk)*128 + nn];
      else if (part == 2) v = Wm1[(512+kk)*128 + nn];
    } else if (n < 280) {                   // a_j(8) a_k(8) c(8)
      int tt = n - 256;
      if (tt < 8)       { if (part == 0) v = Wt1[kk*8 + tt]; }
      else if (tt < 16) { if (part == 0) v = Wt1[(128+kk)*8 + (tt-8)]; }
      else {
        int t = tt - 16;
        if (part == 0)      v = Wt1[(256+kk)*8 + t];
        else if (part == 2) v = Wt1[(384+kk)*8 + t] + Wt1[(512+kk)*8 + t] + Wt1[(640+kk)*8 + t];
        else if (part == 3) v = Wt1[(768+kk)*8 + t];
      }
    }
    WbT[idx] = f2bf(v);
    return;
  }
  idx -= 147456;
  if (idx < 163840) {                       // WgrT: 256*640
    int n = idx / 640, k = idx - n*640;
    int part = k >> 7, kk = k & 127;
    float v = 0.f;
    if (n < 128) {
      int r = (part==0) ? kk : (part==1) ? (128+kk) : (part==2) ? (384+kk)
                        : (part==3) ? (512+kk) : (256+kk);
      v = Wg1[r*128 + n];
    } else {
      int nn = n - 128;
      if (part == 0)      v = Wr[kk*128 + nn];
      else if (part == 1) v = Wr[(128+kk)*128 + nn];
      else if (part == 4) v = Wr[(256+kk)*128 + nn];
    }
    WgrT[idx] = f2bf(v);
    return;
  }
  idx -= 163840;
  if (idx < 16384) { int n = idx >> 7, k = idx & 127; Wm2T[idx] = f2bf(Wm2[k*128 + n]); return; }
  idx -= 16384;
  if (idx < 16384) { int n = idx >> 7, k = idx & 127; Wm3T[idx] = f2bf(Wm3[k*128 + n]); return; }
  idx -= 16384;
  {                                         // gin cols 0:512
    int row = idx >> 9, k = idx & 511;
    int part = k >> 7, kk = k & 127;
    float v;
    if (part == 0)      v = node[row*128 + kk];
    else if (part == 1) v = prev[row*128 + kk];
    else if (part == 2) v = edge[row*128 + kk];
    else                v = graph[(row >> 8)*128 + kk];
    gin[row*640 + k] = f2bf(v);
  }
}

// ---------------------------------------------------------------------------
// G1: uvt[1024][288] = gin[:,0:512] @ WbT^T  (K split across 4 waves)
// ---------------------------------------------------------------------------
__global__ __launch_bounds__(256) void gemm_uvt_kernel(const u16* __restrict__ gin,
                                                       const u16* __restrict__ WbT,
                                                       float* __restrict__ uvt)
{
  int m0 = blockIdx.x * 16, n0 = blockIdx.y * 16;
  int tid = threadIdx.x;
  int w = tid >> 6, lane = tid & 63;
  int c = lane & 15, g = lane >> 4;
  __shared__ float cpart[4][16][17];
  const u16* arow = gin + (size_t)(m0 + c) * 640;
  const u16* brow = WbT + (size_t)(n0 + c) * 512;
  f32x4 acc = {0.f, 0.f, 0.f, 0.f};
#pragma unroll
  for (int kk = 0; kk < 4; ++kk) {
    int k0 = w*4 + kk;
    s16x8 a = *reinterpret_cast<const s16x8*>(arow + k0*32 + g*8);
    s16x8 b = *reinterpret_cast<const s16x8*>(brow + k0*32 + g*8);
    acc = MFMA16(a, b, acc);
  }
#pragma unroll
  for (int r = 0; r < 4; ++r) cpart[w][g*4 + r][c] = acc[r];
  __syncthreads();
  int row = tid >> 4, col = tid & 15;
  float s = cpart[0][row][col] + cpart[1][row][col]
          + cpart[2][row][col] + cpart[3][row][col];
  uvt[(size_t)(m0 + row) * 288 + n0 + col] = s;
}

// ---------------------------------------------------------------------------
// msgmax v10: LDS-minimal dataflow. Block = one i-row, 4 waves = 2 pairs.
// Wave (ch=w&1, jp=w>>1): owns output cols [ch*64, ch*64+64) (mt=4), handles
// j-tile 2*it+jp each iteration. a1 built LANE-LOCAL in registers (zero LDS;
// 2x redundant within a pair). GEMM1 B from regs. Only h2 crosses LDS:
// 4 b64 writes + 4 b128 reads per wave-iter (0.25 reads/MFMA vs v5's 1.0 —
// v5-family was at the LDS-throughput roofline ~34us). One softbar/iter,
// h2 double-buffered. Cross-pair max merge via 512B LDS at end.
// Blocks 0..3 also compute maxat (folded; saves one launch).
// ---------------------------------------------------------------------------
__global__ __launch_bounds__(256) void msgmax_kernel(const float* __restrict__ uvt,
    const u16* __restrict__ Wm2T, const u16* __restrict__ Wm3T,
    const float* __restrict__ bm1, const float* __restrict__ bm2,
    const float* __restrict__ bm3, u16* __restrict__ gin, float* __restrict__ mjk)
{
  const int row = blockIdx.x;
  const int b   = row >> 8;
  const int tid = threadIdx.x;
  const int w   = tid >> 6;
  const int lane = tid & 63;
  const int c = lane & 15, g = lane >> 4;
  const int ch = w & 1, jp = w >> 1;
  const int colbase = ch * 64;

  __shared__ u16 h2s[2][2][16][136];   // [buf][jp][j(c)][128 + 8 pad]
  __shared__ float pm[2][2][64];       // [jp][ch][col in 64]
  __shared__ float part[4][16];        // maxat scratch

  // persistent weight A-fragments (swapped GEMM): 4 m-tiles (64 cols)
  s16x8 wb2[4][4], wb3[4][4];          // [k0][mt]
#pragma unroll
  for (int mt = 0; mt < 4; ++mt) {
    int col = colbase + mt*16 + c;
#pragma unroll
    for (int k0 = 0; k0 < 4; ++k0) {
      wb2[k0][mt] = *reinterpret_cast<const s16x8*>(Wm2T + col*128 + k0*32 + g*8);
      wb3[k0][mt] = *reinterpret_cast<const s16x8*>(Wm3T + col*128 + k0*32 + g*8);
    }
  }

  // u (+bm1): full-k lane slice (k = k0*32 + g*8 + 0..7)
  const f32x4 z4 = {0.f, 0.f, 0.f, 0.f};
  f32x4 uf[4][2];
  {
    const float* urow = uvt + (size_t)row * 288;
#pragma unroll
    for (int k0 = 0; k0 < 4; ++k0) {
      int off = k0*32 + g*8;
      uf[k0][0] = *reinterpret_cast<const f32x4*>(urow + off)
                + *reinterpret_cast<const f32x4*>(bm1 + off);
      uf[k0][1] = *reinterpret_cast<const f32x4*>(urow + off + 4)
                + *reinterpret_cast<const f32x4*>(bm1 + off + 4);
    }
  }

  const float* vb = uvt + (size_t)(b*256) * 288 + 128;
  f32x4 mmax[4];
#pragma unroll
  for (int mt = 0; mt < 4; ++mt) mmax[mt] = {-1e30f, -1e30f, -1e30f, -1e30f};

  for (int it = 0; it < 8; ++it) {
    const int buf = it & 1;
    const int tj = it*2 + jp;

    // ---- build lane-local a1 B-frags (j = tj*16 + c, full k) ----
    const float* vrow = vb + (size_t)(tj*16 + c) * 288 + g*8;
    s16x8 a1f[4];
#pragma unroll
    for (int k0 = 0; k0 < 4; ++k0) {
      f32x4 lo = __builtin_elementwise_max(
                   *reinterpret_cast<const f32x4*>(vrow + k0*32) + uf[k0][0], z4);
      f32x4 hi = __builtin_elementwise_max(
                   *reinterpret_cast<const f32x4*>(vrow + k0*32 + 4) + uf[k0][1], z4);
      s16x8 f;
      f[0] = (short)f2bf(lo[0]); f[1] = (short)f2bf(lo[1]);
      f[2] = (short)f2bf(lo[2]); f[3] = (short)f2bf(lo[3]);
      f[4] = (short)f2bf(hi[0]); f[5] = (short)f2bf(hi[1]);
      f[6] = (short)f2bf(hi[2]); f[7] = (short)f2bf(hi[3]);
      a1f[k0] = f;
    }

    // ---- GEMM1: B from regs, A (weights) from regs ----
    f32x4 acc1[4];
#pragma unroll
    for (int mt = 0; mt < 4; ++mt)
      acc1[mt] = *reinterpret_cast<const f32x4*>(bm2 + colbase + mt*16 + 4*g);
#pragma unroll
    for (int k0 = 0; k0 < 4; ++k0)
#pragma unroll
      for (int mt = 0; mt < 4; ++mt)
        acc1[mt] = MFMA16(wb2[k0][mt], a1f[k0], acc1[mt]);

    // ---- h2 = relu(acc1) -> LDS (pair-shared) ----
#pragma unroll
    for (int mt = 0; mt < 4; ++mt) {
      f32x4 t = __builtin_elementwise_max(acc1[mt], z4);
      uint2 pk = {pk2(t[0], t[1]), pk2(t[2], t[3])};
      *reinterpret_cast<uint2*>(&h2s[buf][jp][c][colbase + mt*16 + 4*g]) = pk;
    }
    softbar();

    // ---- GEMM2: B (h2) from LDS, 4 reads feed 16 MFMA ----
    f32x4 acc2[4] = {z4, z4, z4, z4};
#pragma unroll
    for (int k0 = 0; k0 < 4; ++k0) {
      s16x8 a2 = *reinterpret_cast<const s16x8*>(&h2s[buf][jp][c][k0*32 + g*8]);
#pragma unroll
      for (int mt = 0; mt < 4; ++mt)
        acc2[mt] = MFMA16(wb3[k0][mt], a2, acc2[mt]);
    }
#pragma unroll
    for (int mt = 0; mt < 4; ++mt)
      mmax[mt] = __builtin_elementwise_max(mmax[mt], acc2[mt]);
  }

  // reduce over the 16 j-lanes (c bits) within the wave
#pragma unroll
  for (int mt = 0; mt < 4; ++mt) {
#pragma unroll
    for (int off = 1; off < 16; off <<= 1) {
      mmax[mt][0] = fmaxf(mmax[mt][0], __shfl_xor(mmax[mt][0], off));
      mmax[mt][1] = fmaxf(mmax[mt][1], __shfl_xor(mmax[mt][1], off));
      mmax[mt][2] = fmaxf(mmax[mt][2], __shfl_xor(mmax[mt][2], off));
      mmax[mt][3] = fmaxf(mmax[mt][3], __shfl_xor(mmax[mt][3], off));
    }
  }
  // cross-pair (jp) merge via LDS
  if (c == 0) {
#pragma unroll
    for (int mt = 0; mt < 4; ++mt)
#pragma unroll
      for (int r = 0; r < 4; ++r)
        pm[jp][ch][mt*16 + 4*g + r] = mmax[mt][r];
  }
  __syncthreads();
  if (jp == 0 && c == 0) {
#pragma unroll
    for (int mt = 0; mt < 4; ++mt) {
      int x = mt*16 + 4*g;
      int col = colbase + x;
      float m0v = fmaxf(pm[0][ch][x],   pm[1][ch][x])   + bm3[col];
      float m1v = fmaxf(pm[0][ch][x+1], pm[1][ch][x+1]) + bm3[col+1];
      float m2v = fmaxf(pm[0][ch][x+2], pm[1][ch][x+2]) + bm3[col+2];
      float m3v = fmaxf(pm[0][ch][x+3], pm[1][ch][x+3]) + bm3[col+3];
      uint2 pk = {pk2(m0v, m1v), pk2(m2v, m3v)};
      *reinterpret_cast<uint2*>(gin + (size_t)row*640 + 512 + col) = pk;
    }
  }

  // ---- folded maxat: blocks 0..3 compute per-batch max of a_j,a_k ----
  if (row < 4) {
    __syncthreads();
    int rr = row*256 + tid;
    float v[16];
#pragma unroll
    for (int t = 0; t < 16; ++t) v[t] = uvt[(size_t)rr*288 + 256 + t];
#pragma unroll
    for (int off = 32; off >= 1; off >>= 1) {
#pragma unroll
      for (int t = 0; t < 16; ++t) v[t] = fmaxf(v[t], __shfl_xor(v[t], off));
    }
    int wid = tid >> 6;
    if ((tid & 63) == 0) {
#pragma unroll
      for (int t = 0; t < 16; ++t) part[wid][t] = v[t];
    }
    __syncthreads();
    if (tid < 16)
      mjk[row*16 + tid] = fmaxf(fmaxf(part[0][tid], part[1][tid]),
                                fmaxf(part[2][tid], part[3][tid]));
  }
}

// ---------------------------------------------------------------------------
// G2: [r1 | h_i] = gin(K=640) @ WgrT^T — K split across 4 waves (5 each)
// ---------------------------------------------------------------------------
__global__ __launch_bounds__(256) void gemm_gate_kernel(const u16* __restrict__ gin,
                                 const u16* __restrict__ WgrT,
                                 const float* __restrict__ bg1, const float* __restrict__ br,
                                 float* __restrict__ r1, float* __restrict__ hi)
{
  int m0 = blockIdx.x * 16, n0 = blockIdx.y * 16;
  int tid = threadIdx.x;
  int w = tid >> 6, lane = tid & 63;
  int c = lane & 15, g = lane >> 4;
  __shared__ float cpart[4][16][17];
  const u16* arow = gin  + (size_t)(m0 + c) * 640;
  const u16* brow = WgrT + (size_t)(n0 + c) * 640;
  f32x4 acc = {0.f, 0.f, 0.f, 0.f};
#pragma unroll
  for (int kk = 0; kk < 5; ++kk) {
    int k0 = w*5 + kk;
    s16x8 a = *reinterpret_cast<const s16x8*>(arow + k0*32 + g*8);
    s16x8 b = *reinterpret_cast<const s16x8*>(brow + k0*32 + g*8);
    acc = MFMA16(a, b, acc);
  }
#pragma unroll
  for (int r = 0; r < 4; ++r) cpart[w][g*4 + r][c] = acc[r];
  __syncthreads();
  int row = tid >> 4, col = tid & 15;
  float s = cpart[0][row][col] + cpart[1][row][col]
          + cpart[2][row][col] + cpart[3][row][col];
  int coln = n0 + col;
  int gr = m0 + row;
  if (coln < 128) r1[gr*128 + coln] = fmaxf(s + bg1[coln], 0.f);
  else            hi[gr*128 + coln - 128] = s + br[coln - 128];
}

// ---------------------------------------------------------------------------
// finalize
// ---------------------------------------------------------------------------
__global__ void finalize_kernel(const float* __restrict__ r1, const float* __restrict__ hi,
                                const float* __restrict__ prev, const float* __restrict__ uvt,
                                const float* __restrict__ mjk,
                                const float* __restrict__ Wg2, const float* __restrict__ bg2,
                                const float* __restrict__ bt1, const float* __restrict__ Wt2,
                                const float* __restrict__ bt2, const float* __restrict__ gamma,
                                const float* __restrict__ beta, float* __restrict__ out)
{
  int row = blockIdx.x;
  int h = threadIdx.x;
  int b = row >> 8;
  __shared__ float r1s[128];
  __shared__ float red[4];
  r1s[h] = r1[row*128 + h];
  __syncthreads();
  float glin = bg2[h];
#pragma unroll 8
  for (int k = 0; k < 128; ++k) glin += r1s[k] * Wg2[k*128 + h];
  float g = 1.f / (1.f + __expf(-glin));
  float hg = g * hi[row*128 + h] + (1.f - g) * prev[row*128 + h];

  float s1 = hg, s2 = hg*hg;
#pragma unroll
  for (int off = 1; off < 64; off <<= 1) {
    s1 += __shfl_xor(s1, off);
    s2 += __shfl_xor(s2, off);
  }
  int wid = h >> 6;
  if ((h & 63) == 0) { red[wid] = s1; red[2 + wid] = s2; }
  __syncthreads();
  float mu  = (red[0] + red[1]) * 0.0078125f;
  float ex2 = (red[2] + red[3]) * 0.0078125f;
  float var = ex2 - mu*mu;
  float hn = (hg - mu) * rsqrtf(var + 1e-5f) * gamma[h] + beta[h];
  out[row*128 + h] = hn;

  float o2 = bt2[h];
#pragma unroll
  for (int t = 0; t < 8; ++t) {
    float tv = uvt[(size_t)row*288 + 272 + t] + bt1[t] + mjk[b*16 + t] + mjk[b*16 + 8 + t];
    tv = fmaxf(tv, 0.f);
    o2 += tv * Wt2[t*128 + h];
  }
  out[131072 + row*128 + h] = o2;
}

// ---------------------------------------------------------------------------
extern "C" void kernel_launch(void* const* d_in, const int* in_sizes, int n_in,
                              void* d_out, int out_size, void* d_ws, size_t ws_size,
                              hipStream_t stream) {
  const float* node  = (const float*)d_in[0];
  const float* edge  = (const float*)d_in[1];
  const float* graph = (const float*)d_in[2];
  const float* prev  = (const float*)d_in[3];
  const float* Wm1 = (const float*)d_in[4];
  const float* bm1 = (const float*)d_in[5];
  const float* Wm2 = (const float*)d_in[6];
  const float* bm2 = (const float*)d_in[7];
  const float* Wm3 = (const float*)d_in[8];
  const float* bm3 = (const float*)d_in[9];
  const float* Wg1 = (const float*)d_in[10];
  const float* bg1 = (const float*)d_in[11];
  const float* Wg2 = (const float*)d_in[12];
  const float* bg2 = (const float*)d_in[13];
  const float* Wr  = (const float*)d_in[14];
  const float* br  = (const float*)d_in[15];
  const float* Wt1 = (const float*)d_in[16];
  const float* bt1 = (const float*)d_in[17];
  const float* Wt2 = (const float*)d_in[18];
  const float* bt2 = (const float*)d_in[19];
  const float* gamma = (const float*)d_in[20];
  const float* beta  = (const float*)d_in[21];
  float* out = (float*)d_out;

  char* ws = (char*)d_ws;
  u16*   WbT  = (u16*)(ws + 0);        // 288*512*2   = 294912
  u16*   WgrT = (u16*)(ws + 294912);   // 256*640*2   = 327680
  u16*   Wm2T = (u16*)(ws + 622592);   // 16384*2
  u16*   Wm3T = (u16*)(ws + 655360);   // 16384*2
  u16*   gin  = (u16*)(ws + 688128);   // 1024*640*2  = 1310720
  float* uvt  = (float*)(ws + 1998848);// 1024*288*4  = 1179648
  float* r1   = (float*)(ws + 3178496);// 1024*128*4  = 524288
  float* hi   = (float*)(ws + 3702784);// 524288
  float* mjk  = (float*)(ws + 4227072);// 4*16*4

  prep_kernel<<<3392, 256, 0, stream>>>(Wm1, Wm2, Wm3, Wg1, Wr, Wt1,
                                        node, prev, edge, graph,
                                        WbT, WgrT, Wm2T, Wm3T, gin);
  gemm_uvt_kernel<<<dim3(64, 18), 256, 0, stream>>>(gin, WbT, uvt);
  msgmax_kernel<<<1024, 256, 0, stream>>>(uvt, Wm2T, Wm3T, bm1, bm2, bm3, gin, mjk);
  gemm_gate_kernel<<<dim3(64, 16), 256, 0, stream>>>(gin, WgrT, bg1, br, r1, hi);
  finalize_kernel<<<1024, 128, 0, stream>>>(r1, hi, prev, uvt, mjk,
                                            Wg2, bg2, bt1, Wt2, bt2, gamma, beta, out);
}

// Round 11
// 62.081 us; speedup vs baseline: 1.2859x; 1.2859x over previous
//
#include <hip/hip_runtime.h>
#include <hip/hip_bf16.h>

typedef unsigned short u16;
typedef unsigned int u32;
typedef float f32x4 __attribute__((ext_vector_type(4)));
typedef float f32x16 __attribute__((ext_vector_type(16)));
typedef short s16x8 __attribute__((ext_vector_type(8)));

#define MFMA32(a,b,c) __builtin_amdgcn_mfma_f32_32x32x16_bf16((a),(b),(c),0,0,0)
#define MFMA16(a,b,c) __builtin_amdgcn_mfma_f32_16x16x32_bf16((a),(b),(c),0,0,0)

static __device__ __forceinline__ u16 f2bf(float x){
  union { __hip_bfloat16 b; u16 u; } c;
  c.b = __float2bfloat16(x);
  return c.u;
}
static __device__ __forceinline__ u32 pk2(float a, float b){
  return (u32)f2bf(a) | ((u32)f2bf(b) << 16);
}

// lgkm-only barrier (keeps global loads in flight across barriers)
static __device__ __forceinline__ void softbar() {
  __builtin_amdgcn_sched_barrier(0);
  asm volatile("s_waitcnt lgkmcnt(0)" ::: "memory");
  __builtin_amdgcn_s_barrier();
  __builtin_amdgcn_sched_barrier(0);
}

// ---------------------------------------------------------------------------
// prep: build bf16 transposed/permuted weight buffers + gin[:, 0:512]
// ---------------------------------------------------------------------------
__global__ void prep_kernel(const float* __restrict__ Wm1, const float* __restrict__ Wm2,
                            const float* __restrict__ Wm3, const float* __restrict__ Wg1,
                            const float* __restrict__ Wr,  const float* __restrict__ Wt1,
                            const float* __restrict__ node,const float* __restrict__ prev,
                            const float* __restrict__ edge,const float* __restrict__ graph,
                            u16* __restrict__ WbT, u16* __restrict__ WgrT,
                            u16* __restrict__ Wm2T, u16* __restrict__ Wm3T,
                            u16* __restrict__ gin)
{
  int idx = blockIdx.x * 256 + threadIdx.x;
  if (idx < 147456) {                       // WbT: 288*512
    int n = idx >> 9, k = idx & 511;
    int part = k >> 7, kk = k & 127;
    float v = 0.f;
    if (n < 128) {                          // u = z@W_zi + gb@W_g
      if (part == 0)      v = Wm1[kk*128 + n];
      else if (part == 1) v = Wm1[(128+kk)*128 + n];
      else if (part == 3) v = Wm1[(640+kk)*128 + n];
    } else if (n < 256) {                   // v = z@W_zj + edge@W_e
      int nn = n - 128;
      if (part == 0)      v = Wm1[(256+kk)*128 + nn];
      else if (part == 1) v = Wm1[(384+kk)*128 + nn];
      else if (part == 2) v = Wm1[(512+kk)*128 + nn];
    } else if (n < 280) {                   // a_j(8) a_k(8) c(8)
      int tt = n - 256;
      if (tt < 8)       { if (part == 0) v = Wt1[kk*8 + tt]; }
      else if (tt < 16) { if (part == 0) v = Wt1[(128+kk)*8 + (tt-8)]; }
      else {
        int t = tt - 16;
        if (part == 0)      v = Wt1[(256+kk)*8 + t];
        else if (part == 2) v = Wt1[(384+kk)*8 + t] + Wt1[(512+kk)*8 + t] + Wt1[(640+kk)*8 + t];
        else if (part == 3) v = Wt1[(768+kk)*8 + t];
      }
    }
    WbT[idx] = f2bf(v);
    return;
  }
  idx -= 147456;
  if (idx < 163840) {                       // WgrT: 256*640
    int n = idx / 640, k = idx - n*640;
    int part = k >> 7, kk = k & 127;
    float v = 0.f;
    if (n < 128) {
      int r = (part==0) ? kk : (part==1) ? (128+kk) : (part==2) ? (384+kk)
                        : (part==3) ? (512+kk) : (256+kk);
      v = Wg1[r*128 + n];
    } else {
      int nn = n - 128;
      if (part == 0)      v = Wr[kk*128 + nn];
      else if (part == 1) v = Wr[(128+kk)*128 + nn];
      else if (part == 4) v = Wr[(256+kk)*128 + nn];
    }
    WgrT[idx] = f2bf(v);
    return;
  }
  idx -= 163840;
  if (idx < 16384) { int n = idx >> 7, k = idx & 127; Wm2T[idx] = f2bf(Wm2[k*128 + n]); return; }
  idx -= 16384;
  if (idx < 16384) { int n = idx >> 7, k = idx & 127; Wm3T[idx] = f2bf(Wm3[k*128 + n]); return; }
  idx -= 16384;
  {                                         // gin cols 0:512
    int row = idx >> 9, k = idx & 511;
    int part = k >> 7, kk = k & 127;
    float v;
    if (part == 0)      v = node[row*128 + kk];
    else if (part == 1) v = prev[row*128 + kk];
    else if (part == 2) v = edge[row*128 + kk];
    else                v = graph[(row >> 8)*128 + kk];
    gin[row*640 + k] = f2bf(v);
  }
}

// ---------------------------------------------------------------------------
// G1: uvt[1024][288] = gin[:,0:512] @ WbT^T  (K split across 4 waves)
// ---------------------------------------------------------------------------
__global__ __launch_bounds__(256) void gemm_uvt_kernel(const u16* __restrict__ gin,
                                                       const u16* __restrict__ WbT,
                                                       float* __restrict__ uvt)
{
  int m0 = blockIdx.x * 16, n0 = blockIdx.y * 16;
  int tid = threadIdx.x;
  int w = tid >> 6, lane = tid & 63;
  int c = lane & 15, g = lane >> 4;
  __shared__ float cpart[4][16][17];
  const u16* arow = gin + (size_t)(m0 + c) * 640;
  const u16* brow = WbT + (size_t)(n0 + c) * 512;
  f32x4 acc = {0.f, 0.f, 0.f, 0.f};
#pragma unroll
  for (int kk = 0; kk < 4; ++kk) {
    int k0 = w*4 + kk;
    s16x8 a = *reinterpret_cast<const s16x8*>(arow + k0*32 + g*8);
    s16x8 b = *reinterpret_cast<const s16x8*>(brow + k0*32 + g*8);
    acc = MFMA16(a, b, acc);
  }
#pragma unroll
  for (int r = 0; r < 4; ++r) cpart[w][g*4 + r][c] = acc[r];
  __syncthreads();
  int row = tid >> 4, col = tid & 15;
  float s = cpart[0][row][col] + cpart[1][row][col]
          + cpart[2][row][col] + cpart[3][row][col];
  uvt[(size_t)(m0 + row) * 288 + n0 + col] = s;
}

// ---------------------------------------------------------------------------
// msgmax v11: v5 dataflow with 32x32x16 MFMA — 2x FLOP per fragment read.
// Block = one i-row, 4 waves; wave owns 32 output cols (A-frags of Wm2T/Wm3T
// in regs, 8 k-steps). Per iter (32 j): wave builds a1 j-rows [8w,8w+8)
// (lane: 16 contiguous bf16 = 2 b128 LDS writes), softbar, GEMM1 8 MFMA,
// h2 write, softbar, GEMM2 8 MFMA + running max. Single a1s/h2s buffers
// (write/read pairs straddle barriers). Blocks 0..3 also fold maxat.
// C/D layout (m74): col=lane&31, row=(reg&3)+8*(reg>>2)+4*(lane>>5).
// ---------------------------------------------------------------------------
__global__ __launch_bounds__(256) void msgmax_kernel(const float* __restrict__ uvt,
    const u16* __restrict__ Wm2T, const u16* __restrict__ Wm3T,
    const float* __restrict__ bm1, const float* __restrict__ bm2,
    const float* __restrict__ bm3, u16* __restrict__ gin, float* __restrict__ mjk)
{
  const int row = blockIdx.x;
  const int b   = row >> 8;
  const int tid = threadIdx.x;
  const int w   = tid >> 6;
  const int lane = tid & 63;
  const int jc = lane & 31;        // A-row / B-col / C-col lane index
  const int hi = lane >> 5;        // k-octet selector
  const int colbase = w * 32;

  __shared__ u16 a1s[32][136];     // [j][k 128 + 8 pad]
  __shared__ u16 h2s[32][136];
  __shared__ float part[4][16];

  // weight A-fragments: Wsel[col][k], col = colbase + jc, k = ks*16 + hi*8
  s16x8 wb2[8], wb3[8];
#pragma unroll
  for (int ks = 0; ks < 8; ++ks) {
    wb2[ks] = *reinterpret_cast<const s16x8*>(Wm2T + (colbase + jc)*128 + ks*16 + hi*8);
    wb3[ks] = *reinterpret_cast<const s16x8*>(Wm3T + (colbase + jc)*128 + ks*16 + hi*8);
  }

  // a1 build assignment: lane builds j = w*8 + bj, k = bk..bk+16
  const int bj = lane >> 3;
  const int bk = (lane & 7) * 16;
  f32x4 uf[4];
  {
    const float* urow = uvt + (size_t)row * 288;
#pragma unroll
    for (int q = 0; q < 4; ++q)
      uf[q] = *reinterpret_cast<const f32x4*>(urow + bk + q*4)
            + *reinterpret_cast<const f32x4*>(bm1 + bk + q*4);
  }
  // bm2 per-lane: C rows = colbase + grp*8 + 4*hi + (0..3)
  f32x4 bm2v[4];
#pragma unroll
  for (int grp = 0; grp < 4; ++grp)
    bm2v[grp] = *reinterpret_cast<const f32x4*>(bm2 + colbase + grp*8 + 4*hi);

  const f32x4 z4 = {0.f, 0.f, 0.f, 0.f};
  float mm[16];
#pragma unroll
  for (int i = 0; i < 16; ++i) mm[i] = -1e30f;

  const float* vb = uvt + (size_t)(b*256) * 288 + 128;
  f32x4 vc[4];
#define LOADV(IT) do { \
  const float* p_ = vb + (size_t)((IT)*32 + w*8 + bj) * 288 + bk; \
  vc[0] = *reinterpret_cast<const f32x4*>(p_); \
  vc[1] = *reinterpret_cast<const f32x4*>(p_ + 4); \
  vc[2] = *reinterpret_cast<const f32x4*>(p_ + 8); \
  vc[3] = *reinterpret_cast<const f32x4*>(p_ + 12); } while (0)

  LOADV(0);

  for (int it = 0; it < 8; ++it) {
    // ---- build a1 rows [8w, 8w+8): 16 contiguous bf16 per lane ----
#pragma unroll
    for (int q = 0; q < 2; ++q) {
      f32x4 lo = __builtin_elementwise_max(vc[2*q]   + uf[2*q],   z4);
      f32x4 hn = __builtin_elementwise_max(vc[2*q+1] + uf[2*q+1], z4);
      uint4 pk = {pk2(lo[0], lo[1]), pk2(lo[2], lo[3]),
                  pk2(hn[0], hn[1]), pk2(hn[2], hn[3])};
      *reinterpret_cast<uint4*>(&a1s[w*8 + bj][bk + q*8]) = pk;
    }
    if (it < 7) LOADV(it + 1);
    softbar();                       // a1 ready

    // ---- GEMM1: D[col=j][row=h2col], bias-initialized ----
    f32x16 acc1;
#pragma unroll
    for (int grp = 0; grp < 4; ++grp)
#pragma unroll
      for (int r = 0; r < 4; ++r) acc1[grp*4 + r] = bm2v[grp][r];
#pragma unroll
    for (int ks = 0; ks < 8; ++ks) {
      s16x8 bf = *reinterpret_cast<const s16x8*>(&a1s[jc][ks*16 + hi*8]);
      acc1 = MFMA32(wb2[ks], bf, acc1);
    }
    // h2 = relu(acc1) -> h2s[j][k]: rows colbase+grp*8+4*hi+(0..3)
#pragma unroll
    for (int grp = 0; grp < 4; ++grp) {
      float v0 = fmaxf(acc1[grp*4+0], 0.f), v1 = fmaxf(acc1[grp*4+1], 0.f);
      float v2 = fmaxf(acc1[grp*4+2], 0.f), v3 = fmaxf(acc1[grp*4+3], 0.f);
      uint2 pk = {pk2(v0, v1), pk2(v2, v3)};
      *reinterpret_cast<uint2*>(&h2s[jc][colbase + grp*8 + 4*hi]) = pk;
    }
    softbar();                       // h2 ready

    // ---- GEMM2 + running max ----
    f32x16 acc2 = {0.f,0.f,0.f,0.f,0.f,0.f,0.f,0.f,
                   0.f,0.f,0.f,0.f,0.f,0.f,0.f,0.f};
#pragma unroll
    for (int ks = 0; ks < 8; ++ks) {
      s16x8 bf = *reinterpret_cast<const s16x8*>(&h2s[jc][ks*16 + hi*8]);
      acc2 = MFMA32(wb3[ks], bf, acc2);
    }
#pragma unroll
    for (int i = 0; i < 16; ++i) mm[i] = fmaxf(mm[i], acc2[i]);
  }
#undef LOADV

  // reduce max over j (col = jc, xor stays within 32-lane half)
#pragma unroll
  for (int i = 0; i < 16; ++i) {
    mm[i] = fmaxf(mm[i], __shfl_xor(mm[i], 1));
    mm[i] = fmaxf(mm[i], __shfl_xor(mm[i], 2));
    mm[i] = fmaxf(mm[i], __shfl_xor(mm[i], 4));
    mm[i] = fmaxf(mm[i], __shfl_xor(mm[i], 8));
    mm[i] = fmaxf(mm[i], __shfl_xor(mm[i], 16));
  }
  if (jc == 0) {
#pragma unroll
    for (int grp = 0; grp < 4; ++grp) {
      int col = colbase + grp*8 + 4*hi;
      uint2 pk = {pk2(mm[grp*4+0] + bm3[col],   mm[grp*4+1] + bm3[col+1]),
                  pk2(mm[grp*4+2] + bm3[col+2], mm[grp*4+3] + bm3[col+3])};
      *reinterpret_cast<uint2*>(gin + (size_t)row*640 + 512 + col) = pk;
    }
  }

  // ---- folded maxat: blocks 0..3 compute per-batch max of a_j,a_k ----
  if (row < 4) {
    __syncthreads();
    int rr = row*256 + tid;
    float v[16];
#pragma unroll
    for (int t = 0; t < 16; ++t) v[t] = uvt[(size_t)rr*288 + 256 + t];
#pragma unroll
    for (int off = 32; off >= 1; off >>= 1) {
#pragma unroll
      for (int t = 0; t < 16; ++t) v[t] = fmaxf(v[t], __shfl_xor(v[t], off));
    }
    int wid = tid >> 6;
    if ((tid & 63) == 0) {
#pragma unroll
      for (int t = 0; t < 16; ++t) part[wid][t] = v[t];
    }
    __syncthreads();
    if (tid < 16)
      mjk[row*16 + tid] = fmaxf(fmaxf(part[0][tid], part[1][tid]),
                                fmaxf(part[2][tid], part[3][tid]));
  }
}

// ---------------------------------------------------------------------------
// G2: [r1 | h_i] = gin(K=640) @ WgrT^T — K split across 4 waves (5 each)
// ---------------------------------------------------------------------------
__global__ __launch_bounds__(256) void gemm_gate_kernel(const u16* __restrict__ gin,
                                 const u16* __restrict__ WgrT,
                                 const float* __restrict__ bg1, const float* __restrict__ br,
                                 float* __restrict__ r1, float* __restrict__ hi)
{
  int m0 = blockIdx.x * 16, n0 = blockIdx.y * 16;
  int tid = threadIdx.x;
  int w = tid >> 6, lane = tid & 63;
  int c = lane & 15, g = lane >> 4;
  __shared__ float cpart[4][16][17];
  const u16* arow = gin  + (size_t)(m0 + c) * 640;
  const u16* brow = WgrT + (size_t)(n0 + c) * 640;
  f32x4 acc = {0.f, 0.f, 0.f, 0.f};
#pragma unroll
  for (int kk = 0; kk < 5; ++kk) {
    int k0 = w*5 + kk;
    s16x8 a = *reinterpret_cast<const s16x8*>(arow + k0*32 + g*8);
    s16x8 b = *reinterpret_cast<const s16x8*>(brow + k0*32 + g*8);
    acc = MFMA16(a, b, acc);
  }
#pragma unroll
  for (int r = 0; r < 4; ++r) cpart[w][g*4 + r][c] = acc[r];
  __syncthreads();
  int row = tid >> 4, col = tid & 15;
  float s = cpart[0][row][col] + cpart[1][row][col]
          + cpart[2][row][col] + cpart[3][row][col];
  int coln = n0 + col;
  int gr = m0 + row;
  if (coln < 128) r1[gr*128 + coln] = fmaxf(s + bg1[coln], 0.f);
  else            hi[gr*128 + coln - 128] = s + br[coln - 128];
}

// ---------------------------------------------------------------------------
// finalize
// ---------------------------------------------------------------------------
__global__ void finalize_kernel(const float* __restrict__ r1, const float* __restrict__ hi,
                                const float* __restrict__ prev, const float* __restrict__ uvt,
                                const float* __restrict__ mjk,
                                const float* __restrict__ Wg2, const float* __restrict__ bg2,
                                const float* __restrict__ bt1, const float* __restrict__ Wt2,
                                const float* __restrict__ bt2, const float* __restrict__ gamma,
                                const float* __restrict__ beta, float* __restrict__ out)
{
  int row = blockIdx.x;
  int h = threadIdx.x;
  int b = row >> 8;
  __shared__ float r1s[128];
  __shared__ float red[4];
  r1s[h] = r1[row*128 + h];
  __syncthreads();
  float glin = bg2[h];
#pragma unroll 8
  for (int k = 0; k < 128; ++k) glin += r1s[k] * Wg2[k*128 + h];
  float g = 1.f / (1.f + __expf(-glin));
  float hg = g * hi[row*128 + h] + (1.f - g) * prev[row*128 + h];

  float s1 = hg, s2 = hg*hg;
#pragma unroll
  for (int off = 1; off < 64; off <<= 1) {
    s1 += __shfl_xor(s1, off);
    s2 += __shfl_xor(s2, off);
  }
  int wid = h >> 6;
  if ((h & 63) == 0) { red[wid] = s1; red[2 + wid] = s2; }
  __syncthreads();
  float mu  = (red[0] + red[1]) * 0.0078125f;
  float ex2 = (red[2] + red[3]) * 0.0078125f;
  float var = ex2 - mu*mu;
  float hn = (hg - mu) * rsqrtf(var + 1e-5f) * gamma[h] + beta[h];
  out[row*128 + h] = hn;

  float o2 = bt2[h];
#pragma unroll
  for (int t = 0; t < 8; ++t) {
    float tv = uvt[(size_t)row*288 + 272 + t] + bt1[t] + mjk[b*16 + t] + mjk[b*16 + 8 + t];
    tv = fmaxf(tv, 0.f);
    o2 += tv * Wt2[t*128 + h];
  }
  out[131072 + row*128 + h] = o2;
}

// ---------------------------------------------------------------------------
extern "C" void kernel_launch(void* const* d_in, const int* in_sizes, int n_in,
                              void* d_out, int out_size, void* d_ws, size_t ws_size,
                              hipStream_t stream) {
  const float* node  = (const float*)d_in[0];
  const float* edge  = (const float*)d_in[1];
  const float* graph = (const float*)d_in[2];
  const float* prev  = (const float*)d_in[3];
  const float* Wm1 = (const float*)d_in[4];
  const float* bm1 = (const float*)d_in[5];
  const float* Wm2 = (const float*)d_in[6];
  const float* bm2 = (const float*)d_in[7];
  const float* Wm3 = (const float*)d_in[8];
  const float* bm3 = (const float*)d_in[9];
  const float* Wg1 = (const float*)d_in[10];
  const float* bg1 = (const float*)d_in[11];
  const float* Wg2 = (const float*)d_in[12];
  const float* bg2 = (const float*)d_in[13];
  const float* Wr  = (const float*)d_in[14];
  const float* br  = (const float*)d_in[15];
  const float* Wt1 = (const float*)d_in[16];
  const float* bt1 = (const float*)d_in[17];
  const float* Wt2 = (const float*)d_in[18];
  const float* bt2 = (const float*)d_in[19];
  const float* gamma = (const float*)d_in[20];
  const float* beta  = (const float*)d_in[21];
  float* out = (float*)d_out;

  char* ws = (char*)d_ws;
  u16*   WbT  = (u16*)(ws + 0);        // 288*512*2   = 294912
  u16*   WgrT = (u16*)(ws + 294912);   // 256*640*2   = 327680
  u16*   Wm2T = (u16*)(ws + 622592);   // 16384*2
  u16*   Wm3T = (u16*)(ws + 655360);   // 16384*2
  u16*   gin  = (u16*)(ws + 688128);   // 1024*640*2  = 1310720
  float* uvt  = (float*)(ws + 1998848);// 1024*288*4  = 1179648
  float* r1   = (float*)(ws + 3178496);// 1024*128*4  = 524288
  float* hi   = (float*)(ws + 3702784);// 524288
  float* mjk  = (float*)(ws + 4227072);// 4*16*4

  prep_kernel<<<3392, 256, 0, stream>>>(Wm1, Wm2, Wm3, Wg1, Wr, Wt1,
                                        node, prev, edge, graph,
                                        WbT, WgrT, Wm2T, Wm3T, gin);
  gemm_uvt_kernel<<<dim3(64, 18), 256, 0, stream>>>(gin, WbT, uvt);
  msgmax_kernel<<<1024, 256, 0, stream>>>(uvt, Wm2T, Wm3T, bm1, bm2, bm3, gin, mjk);
  gemm_gate_kernel<<<dim3(64, 16), 256, 0, stream>>>(gin, WgrT, bg1, br, r1, hi);
  finalize_kernel<<<1024, 128, 0, stream>>>(r1, hi, prev, uvt, mjk,
                                            Wg2, bg2, bt1, Wt2, bt2, gamma, beta, out);
}